// Round 11
// baseline (253.684 us; speedup 1.0000x reference)
//
#include <hip/hip_runtime.h>

#define N_NODES 50000
#define IN_DIM  256
#define OUT_DIM 128
#define OD2     64       // packed bf16 pairs / float2 per 128-dim row
#define NBINS   782      // bin = row >> 6  (64 rows per bin)
#define RPB     64
#define CHUNK   2048     // edges per partition block (r11: halved for 2x blocks)
#define EPT     8        // edges per thread in partition (CHUNK/256)
#define CAPBX   1408     // X edges per bin: mean 1024, +12 sigma
#define CAPBA   2600     // adj edges per bin: mean 2048, +12 sigma
#define CSTRIDE 8        // bin counters padded to one 32B sector

typedef unsigned long long u64;

// ---------------------------------------------------------------------------
// bf16 helpers (RNE).
// ---------------------------------------------------------------------------
__device__ __forceinline__ unsigned pack_bf16x2(float a, float b) {
    unsigned ua = __float_as_uint(a), ub = __float_as_uint(b);
    ua = (ua + 0x7fffu + ((ua >> 16) & 1u)) >> 16;
    ub = (ub + 0x7fffu + ((ub >> 16) & 1u)) >> 16;
    return ua | (ub << 16);
}
__device__ __forceinline__ float2 unpack_bf16x2(unsigned u) {
    return make_float2(__uint_as_float(u << 16),
                       __uint_as_float(u & 0xffff0000u));
}

// Edge word (u64): [63:32] = f32 val bits, [31:16] = row, [15:0] = col.
// Packed edge (u32): [31:16] = bf16 val bits, [15:0] = col.

// ---------------------------------------------------------------------------
// Level 1: partition into 782 row-bins.  LDS counting-sort each 2048-edge
// chunk by bin, one global cursor atomic per (block, nonempty bin), write
// runs contiguously (coalesced).  Blocks [0,bx) = X (keep_prob=1 dropout,
// faithful); rest = adj.
// ---------------------------------------------------------------------------
__global__ __launch_bounds__(256) void partition(
        const int* __restrict__ xr, const int* __restrict__ xc,
        const float* __restrict__ xv, const float* __restrict__ dn, int nnz,
        const int* __restrict__ ar, const int* __restrict__ ac,
        const float* __restrict__ av, int ne,
        int* __restrict__ gcur_x, u64* __restrict__ egx,
        int* __restrict__ gcur_a, u64* __restrict__ ega, int bx) {
    __shared__ u64 stage[CHUNK];          // 16 KB
    __shared__ int hist[1024];            // zero-padded past NBINS
    __shared__ int base_l[1024];
    __shared__ int cur_l[1024];
    __shared__ int gbase[1024];
    __shared__ int tsum[256];

    int t = threadIdx.x;
    const int *rows, *cols;
    const float *vals, *noise = nullptr;
    int n, c0, cap;
    int* gcur;
    u64* eg;
    if (blockIdx.x < bx) {
        rows = xr; cols = xc; vals = xv; noise = dn; n = nnz;
        c0 = blockIdx.x * CHUNK; gcur = gcur_x; eg = egx; cap = CAPBX;
    } else {
        rows = ar; cols = ac; vals = av; n = ne;
        c0 = (blockIdx.x - bx) * CHUNK; gcur = gcur_a; eg = ega; cap = CAPBA;
    }

    for (int i = t; i < 1024; i += 256) hist[i] = 0;
    __syncthreads();

    u64 w[EPT];
    bool ok[EPT];
    #pragma unroll
    for (int j = 0; j < EPT; ++j) {
        int i = c0 + j * 256 + t;
        ok[j] = (i < n);
        if (ok[j]) {
            int r = rows[i], c = cols[i];
            float v = vals[i];
            if (noise) v *= floorf(1.0f + noise[i]);
            w[j] = ((u64)__float_as_uint(v) << 32) | ((unsigned)r << 16) | (unsigned)c;
            atomicAdd(&hist[r >> 6], 1);
        }
    }
    __syncthreads();

    // exclusive scan of hist (1024 entries, 4/thread + Hillis-Steele)
    int s0 = hist[t * 4], s1 = hist[t * 4 + 1], s2 = hist[t * 4 + 2], s3 = hist[t * 4 + 3];
    int tot = s0 + s1 + s2 + s3;
    tsum[t] = tot;
    __syncthreads();
    for (int off = 1; off < 256; off <<= 1) {
        int v = (t >= off) ? tsum[t - off] : 0;
        __syncthreads();
        tsum[t] += v;
        __syncthreads();
    }
    int pfx = tsum[t] - tot;
    base_l[t * 4]     = pfx;
    base_l[t * 4 + 1] = pfx + s0;
    base_l[t * 4 + 2] = pfx + s0 + s1;
    base_l[t * 4 + 3] = pfx + s0 + s1 + s2;
    cur_l[t * 4]     = base_l[t * 4];
    cur_l[t * 4 + 1] = base_l[t * 4 + 1];
    cur_l[t * 4 + 2] = base_l[t * 4 + 2];
    cur_l[t * 4 + 3] = base_l[t * 4 + 3];
    __syncthreads();

    // one global cursor atomic per nonempty bin
    for (int i = t; i < NBINS; i += 256) {
        int c = hist[i];
        if (c) gbase[i] = atomicAdd(&gcur[i * CSTRIDE], c);
    }
    // scatter into LDS staging (sorted by bin)
    #pragma unroll
    for (int j = 0; j < EPT; ++j) {
        if (ok[j]) {
            int b = (int)((w[j] >> 22) & 0x3ff);
            int p = atomicAdd(&cur_l[b], 1);
            stage[p] = w[j];
        }
    }
    __syncthreads();

    // coalesced run write-out
    int cnt = min(n - c0, CHUNK);
    for (int p = t; p < cnt; p += 256) {
        u64 ww = stage[p];
        int b = (int)((ww >> 22) & 0x3ff);
        int g = gbase[b] + (p - base_l[b]);
        if (g < cap) eg[(size_t)b * cap + g] = ww;
    }
}

// ---------------------------------------------------------------------------
// Level 2 (X): row-sort within each X bin -> exact per-row CSR segments,
// repacked to 4 B edges, fully coalesced writes.
// ---------------------------------------------------------------------------
__global__ __launch_bounds__(256) void rowsort_x(
        const int* __restrict__ gcur_x, const u64* __restrict__ egx,
        unsigned* __restrict__ e4x, int* __restrict__ rptr_x, int* __restrict__ rcnt_x) {
    __shared__ u64 stage[CAPBX];        // 11.3 KB
    __shared__ unsigned sorted[CAPBX];  // 5.6 KB
    __shared__ int hist[64], ptrl[64], curl[64];

    int t = threadIdx.x;
    int bin = blockIdx.x;
    int cnt = min(gcur_x[bin * CSTRIDE], CAPBX);
    size_t base = (size_t)bin * CAPBX;

    for (int i = t; i < cnt; i += 256) stage[i] = egx[base + i];
    if (t < 64) hist[t] = 0;
    __syncthreads();

    for (int i = t; i < cnt; i += 256)
        atomicAdd(&hist[(int)((stage[i] >> 16) & 63)], 1);
    __syncthreads();

    if (t == 0) {
        int s = 0;
        for (int r = 0; r < 64; ++r) { ptrl[r] = s; s += hist[r]; }
    }
    __syncthreads();
    if (t < 64) curl[t] = ptrl[t];
    __syncthreads();

    for (int i = t; i < cnt; i += 256) {
        u64 w = stage[i];
        int r = (int)((w >> 16) & 63);
        int p = atomicAdd(&curl[r], 1);
        unsigned uv = (unsigned)(w >> 32);
        uv = (uv + 0x7fffu + ((uv >> 16) & 1u)) & 0xffff0000u;   // bf16 in hi16
        sorted[p] = (unsigned)(w & 0xffffu) | uv;
    }
    __syncthreads();

    for (int i = t; i < cnt; i += 256) e4x[base + i] = sorted[i];
    if (t < 64) {
        int g = bin * RPB + t;
        if (g < N_NODES) {
            rptr_x[g] = (int)base + ptrl[t];
            rcnt_x[g] = hist[t];
        }
    }
}

// ---------------------------------------------------------------------------
// K3 fused: blocks [0, NBINS) row-sort the adj bins (independent of spmm_w);
// blocks [NBINS, ...) run spmm_w: h(bf16) = X * W, one wave per row, W
// gathered as float2 from global (128 KB -> L2-resident), 8-way unroll.
// ---------------------------------------------------------------------------
__global__ __launch_bounds__(256) void k3_rsa_spmmw(
        const int* __restrict__ gcur_a, const u64* __restrict__ ega,
        unsigned* __restrict__ e4a, int* __restrict__ rptr_a, int* __restrict__ rcnt_a,
        const int* __restrict__ rptr_x, const int* __restrict__ rcnt_x,
        const unsigned* __restrict__ e4x,
        const float2* __restrict__ Wt, unsigned* __restrict__ hpk) {
    __shared__ u64 stage[CAPBA];        // 20.8 KB
    __shared__ unsigned sorted[CAPBA];  // 10.4 KB
    __shared__ int hist[64], ptrl[64], curl[64];

    int t = threadIdx.x;
    if (blockIdx.x < NBINS) {
        // ---- rowsort_a -----------------------------------------------------
        int bin = blockIdx.x;
        int cnt = min(gcur_a[bin * CSTRIDE], CAPBA);
        size_t base = (size_t)bin * CAPBA;

        for (int i = t; i < cnt; i += 256) stage[i] = ega[base + i];
        if (t < 64) hist[t] = 0;
        __syncthreads();

        for (int i = t; i < cnt; i += 256)
            atomicAdd(&hist[(int)((stage[i] >> 16) & 63)], 1);
        __syncthreads();

        if (t == 0) {
            int s = 0;
            for (int r = 0; r < 64; ++r) { ptrl[r] = s; s += hist[r]; }
        }
        __syncthreads();
        if (t < 64) curl[t] = ptrl[t];
        __syncthreads();

        for (int i = t; i < cnt; i += 256) {
            u64 w = stage[i];
            int r = (int)((w >> 16) & 63);
            int p = atomicAdd(&curl[r], 1);
            unsigned uv = (unsigned)(w >> 32);
            uv = (uv + 0x7fffu + ((uv >> 16) & 1u)) & 0xffff0000u;
            sorted[p] = (unsigned)(w & 0xffffu) | uv;
        }
        __syncthreads();

        for (int i = t; i < cnt; i += 256) e4a[base + i] = sorted[i];
        if (t < 64) {
            int g = bin * RPB + t;
            if (g < N_NODES) {
                rptr_a[g] = (int)base + ptrl[t];
                rcnt_a[g] = hist[t];
            }
        }
        return;
    }

    // ---- spmm_w: one wave per row, 8-way unrolled W gathers ----------------
    int wave = ((blockIdx.x - NBINS) * 256 + t) >> 6;
    int lane = t & 63;
    if (wave >= N_NODES) return;

    int s   = rptr_x[wave];
    int end = s + rcnt_x[wave];
    float2 acc = make_float2(0.0f, 0.0f);

    int e = s;
    for (; e + 7 < end; e += 8) {
        unsigned u0 = e4x[e],     u1 = e4x[e + 1], u2 = e4x[e + 2], u3 = e4x[e + 3];
        unsigned u4 = e4x[e + 4], u5 = e4x[e + 5], u6 = e4x[e + 6], u7 = e4x[e + 7];
        float2 a0 = Wt[(size_t)(u0 & 0xffffu) * OD2 + lane];
        float2 a1 = Wt[(size_t)(u1 & 0xffffu) * OD2 + lane];
        float2 a2 = Wt[(size_t)(u2 & 0xffffu) * OD2 + lane];
        float2 a3 = Wt[(size_t)(u3 & 0xffffu) * OD2 + lane];
        float2 a4 = Wt[(size_t)(u4 & 0xffffu) * OD2 + lane];
        float2 a5 = Wt[(size_t)(u5 & 0xffffu) * OD2 + lane];
        float2 a6 = Wt[(size_t)(u6 & 0xffffu) * OD2 + lane];
        float2 a7 = Wt[(size_t)(u7 & 0xffffu) * OD2 + lane];
        float v0 = __uint_as_float(u0 & 0xffff0000u), v1 = __uint_as_float(u1 & 0xffff0000u);
        float v2 = __uint_as_float(u2 & 0xffff0000u), v3 = __uint_as_float(u3 & 0xffff0000u);
        float v4 = __uint_as_float(u4 & 0xffff0000u), v5 = __uint_as_float(u5 & 0xffff0000u);
        float v6 = __uint_as_float(u6 & 0xffff0000u), v7 = __uint_as_float(u7 & 0xffff0000u);
        acc.x += v0 * a0.x + v1 * a1.x + v2 * a2.x + v3 * a3.x
               + v4 * a4.x + v5 * a5.x + v6 * a6.x + v7 * a7.x;
        acc.y += v0 * a0.y + v1 * a1.y + v2 * a2.y + v3 * a3.y
               + v4 * a4.y + v5 * a5.y + v6 * a6.y + v7 * a7.y;
    }
    for (; e < end; ++e) {
        unsigned u0 = e4x[e];
        float2 a = Wt[(size_t)(u0 & 0xffffu) * OD2 + lane];
        float v0 = __uint_as_float(u0 & 0xffff0000u);
        acc.x += v0 * a.x;
        acc.y += v0 * a.y;
    }
    hpk[(size_t)wave * OD2 + lane] = pack_bf16x2(acc.x, acc.y);
}

// ---------------------------------------------------------------------------
// SpMM 2 + ReLU: out = relu(A * h).  One wave per row; gathers packed-bf16
// h rows (256 B/row); 8-way unroll; f32 accumulate; f32 out.
// ---------------------------------------------------------------------------
__global__ void spmm_h(const int* __restrict__ rptr, const int* __restrict__ rcnt,
                       const unsigned* __restrict__ e4,
                       const unsigned* __restrict__ hpk, float2* __restrict__ outm,
                       int nrows) {
    int wave = (blockIdx.x * blockDim.x + threadIdx.x) >> 6;
    int lane = threadIdx.x & 63;
    if (wave >= nrows) return;

    int s   = rptr[wave];
    int end = s + rcnt[wave];
    float2 acc = make_float2(0.0f, 0.0f);

    int e = s;
    for (; e + 7 < end; e += 8) {
        unsigned u0 = e4[e],     u1 = e4[e + 1], u2 = e4[e + 2], u3 = e4[e + 3];
        unsigned u4 = e4[e + 4], u5 = e4[e + 5], u6 = e4[e + 6], u7 = e4[e + 7];
        unsigned h0 = hpk[(size_t)(u0 & 0xffffu) * OD2 + lane];
        unsigned h1 = hpk[(size_t)(u1 & 0xffffu) * OD2 + lane];
        unsigned h2 = hpk[(size_t)(u2 & 0xffffu) * OD2 + lane];
        unsigned h3 = hpk[(size_t)(u3 & 0xffffu) * OD2 + lane];
        unsigned h4 = hpk[(size_t)(u4 & 0xffffu) * OD2 + lane];
        unsigned h5 = hpk[(size_t)(u5 & 0xffffu) * OD2 + lane];
        unsigned h6 = hpk[(size_t)(u6 & 0xffffu) * OD2 + lane];
        unsigned h7 = hpk[(size_t)(u7 & 0xffffu) * OD2 + lane];
        float v0 = __uint_as_float(u0 & 0xffff0000u), v1 = __uint_as_float(u1 & 0xffff0000u);
        float v2 = __uint_as_float(u2 & 0xffff0000u), v3 = __uint_as_float(u3 & 0xffff0000u);
        float v4 = __uint_as_float(u4 & 0xffff0000u), v5 = __uint_as_float(u5 & 0xffff0000u);
        float v6 = __uint_as_float(u6 & 0xffff0000u), v7 = __uint_as_float(u7 & 0xffff0000u);
        float2 a0 = unpack_bf16x2(h0), a1 = unpack_bf16x2(h1);
        float2 a2 = unpack_bf16x2(h2), a3 = unpack_bf16x2(h3);
        float2 a4 = unpack_bf16x2(h4), a5 = unpack_bf16x2(h5);
        float2 a6 = unpack_bf16x2(h6), a7 = unpack_bf16x2(h7);
        acc.x += v0 * a0.x + v1 * a1.x + v2 * a2.x + v3 * a3.x
               + v4 * a4.x + v5 * a5.x + v6 * a6.x + v7 * a7.x;
        acc.y += v0 * a0.y + v1 * a1.y + v2 * a2.y + v3 * a3.y
               + v4 * a4.y + v5 * a5.y + v6 * a6.y + v7 * a7.y;
    }
    for (; e < end; ++e) {
        unsigned u0 = e4[e];
        float2 a = unpack_bf16x2(hpk[(size_t)(u0 & 0xffffu) * OD2 + lane]);
        float v0 = __uint_as_float(u0 & 0xffff0000u);
        acc.x += v0 * a.x;
        acc.y += v0 * a.y;
    }
    acc.x = fmaxf(acc.x, 0.0f);
    acc.y = fmaxf(acc.y, 0.0f);
    outm[(size_t)wave * OD2 + lane] = acc;
}

extern "C" void kernel_launch(void* const* d_in, const int* in_sizes, int n_in,
                              void* d_out, int out_size, void* d_ws, size_t ws_size,
                              hipStream_t stream) {
    const int*   x_rows     = (const int*)d_in[0];
    const int*   x_cols     = (const int*)d_in[1];
    const float* x_vals     = (const float*)d_in[2];
    const float* drop_noise = (const float*)d_in[3];
    const int*   adj_rows   = (const int*)d_in[4];
    const int*   adj_cols   = (const int*)d_in[5];
    const float* adj_vals   = (const float*)d_in[6];
    const float* W          = (const float*)d_in[7];

    const int nnz = in_sizes[0];   // 800000
    const int ne  = in_sizes[4];   // 1600000

    float* out = (float*)d_out;

    // ---- workspace layout (~52 MB) -----------------------------------------
    char* base = (char*)d_ws;
    unsigned* hpk = (unsigned*)base;                                    // 12.8 MB
    u64* egx = (u64*)(base + (size_t)N_NODES * OD2 * sizeof(unsigned)); // 8.8 MB
    u64* ega = egx + (size_t)NBINS * CAPBX;                             // 16.3 MB
    unsigned* e4x = (unsigned*)(ega + (size_t)NBINS * CAPBA);           // 4.4 MB
    unsigned* e4a = e4x + (size_t)NBINS * CAPBX;                        // 8.1 MB
    int* rptr_x = (int*)(e4a + (size_t)NBINS * CAPBA);                  // 200 KB
    int* rcnt_x = rptr_x + N_NODES;
    int* rptr_a = rcnt_x + N_NODES;
    int* rcnt_a = rptr_a + N_NODES;
    int* gcur_x = rcnt_a + N_NODES;                                     // 25 KB
    int* gcur_a = gcur_x + NBINS * CSTRIDE;

    hipMemsetAsync(gcur_x, 0, 2 * (size_t)NBINS * CSTRIDE * sizeof(int), stream);

    const int BXC = (nnz + CHUNK - 1) / CHUNK;   // 391
    const int BAC = (ne + CHUNK - 1) / CHUNK;    // 782
    const int BSPW = (N_NODES * 64 + 255) / 256; // 12500

    // L1: bin partition (coalesced run writes)
    partition<<<BXC + BAC, 256, 0, stream>>>(
        x_rows, x_cols, x_vals, drop_noise, nnz,
        adj_rows, adj_cols, adj_vals, ne,
        gcur_x, egx, gcur_a, ega, BXC);

    // L2 (X): per-row CSR within X bins
    rowsort_x<<<NBINS, 256, 0, stream>>>(gcur_x, egx, e4x, rptr_x, rcnt_x);

    // K3: rowsort_a  ||  spmm_w (independent -> overlap in one launch)
    k3_rsa_spmmw<<<NBINS + BSPW, 256, 0, stream>>>(
        gcur_a, ega, e4a, rptr_a, rcnt_a,
        rptr_x, rcnt_x, e4x, (const float2*)W, hpk);

    // K4: out = relu(A * h)
    spmm_h<<<BSPW, 256, 0, stream>>>(rptr_a, rcnt_a, e4a, hpk,
                                     (float2*)out, N_NODES);
}

// Round 12
// 219.822 us; speedup vs baseline: 1.1540x; 1.1540x over previous
//
#include <hip/hip_runtime.h>

#define N_NODES 50000
#define IN_DIM  256
#define OUT_DIM 128
#define OD2     64       // packed bf16 pairs / float2 per 128-dim row
#define NBINS   782      // bin = row >> 6  (64 rows per bin)
#define RPB     64
#define CHUNK   4096     // edges per partition block (round-10 proven)
#define EPT     16       // edges per thread in partition (CHUNK/256)
#define CAPBX   1408     // X edges per bin: mean 1024, +12 sigma
#define CAPBA   2600     // adj edges per bin: mean 2048, +12 sigma
#define CSTRIDE 8        // bin counters padded to one 32B sector
#define SBINS   512      // rowsort bins: row6 * 8 + col-phase3

typedef unsigned long long u64;

// ---------------------------------------------------------------------------
// bf16 helpers (RNE).
// ---------------------------------------------------------------------------
__device__ __forceinline__ unsigned pack_bf16x2(float a, float b) {
    unsigned ua = __float_as_uint(a), ub = __float_as_uint(b);
    ua = (ua + 0x7fffu + ((ua >> 16) & 1u)) >> 16;
    ub = (ub + 0x7fffu + ((ub >> 16) & 1u)) >> 16;
    return ua | (ub << 16);
}
__device__ __forceinline__ float2 unpack_bf16x2(unsigned u) {
    return make_float2(__uint_as_float(u << 16),
                       __uint_as_float(u & 0xffff0000u));
}

// Edge word (u64): [63:32] = f32 val bits, [31:16] = row, [15:0] = col.
// Packed edge (u32): [31:16] = bf16 val bits, [15:0] = col.

// ---------------------------------------------------------------------------
// Level 1: partition into 782 row-bins.  LDS counting-sort each 4096-edge
// chunk by bin, one global cursor atomic per (block, nonempty bin), write
// runs contiguously (coalesced).  Blocks [0,bx) = X (keep_prob=1 dropout,
// faithful); rest = adj.  (Round-10 proven version.)
// ---------------------------------------------------------------------------
__global__ __launch_bounds__(256) void partition(
        const int* __restrict__ xr, const int* __restrict__ xc,
        const float* __restrict__ xv, const float* __restrict__ dn, int nnz,
        const int* __restrict__ ar, const int* __restrict__ ac,
        const float* __restrict__ av, int ne,
        int* __restrict__ gcur_x, u64* __restrict__ egx,
        int* __restrict__ gcur_a, u64* __restrict__ ega, int bx) {
    __shared__ u64 stage[CHUNK];          // 32 KB
    __shared__ int hist[1024];            // zero-padded past NBINS
    __shared__ int base_l[1024];
    __shared__ int cur_l[1024];
    __shared__ int gbase[1024];
    __shared__ int tsum[256];

    int t = threadIdx.x;
    const int *rows, *cols;
    const float *vals, *noise = nullptr;
    int n, c0, cap;
    int* gcur;
    u64* eg;
    if (blockIdx.x < bx) {
        rows = xr; cols = xc; vals = xv; noise = dn; n = nnz;
        c0 = blockIdx.x * CHUNK; gcur = gcur_x; eg = egx; cap = CAPBX;
    } else {
        rows = ar; cols = ac; vals = av; n = ne;
        c0 = (blockIdx.x - bx) * CHUNK; gcur = gcur_a; eg = ega; cap = CAPBA;
    }

    for (int i = t; i < 1024; i += 256) hist[i] = 0;
    __syncthreads();

    u64 w[EPT];
    bool ok[EPT];
    #pragma unroll
    for (int j = 0; j < EPT; ++j) {
        int i = c0 + j * 256 + t;
        ok[j] = (i < n);
        if (ok[j]) {
            int r = rows[i], c = cols[i];
            float v = vals[i];
            if (noise) v *= floorf(1.0f + noise[i]);
            w[j] = ((u64)__float_as_uint(v) << 32) | ((unsigned)r << 16) | (unsigned)c;
            atomicAdd(&hist[r >> 6], 1);
        }
    }
    __syncthreads();

    // exclusive scan of hist (1024 entries, 4/thread + Hillis-Steele)
    int s0 = hist[t * 4], s1 = hist[t * 4 + 1], s2 = hist[t * 4 + 2], s3 = hist[t * 4 + 3];
    int tot = s0 + s1 + s2 + s3;
    tsum[t] = tot;
    __syncthreads();
    for (int off = 1; off < 256; off <<= 1) {
        int v = (t >= off) ? tsum[t - off] : 0;
        __syncthreads();
        tsum[t] += v;
        __syncthreads();
    }
    int pfx = tsum[t] - tot;
    base_l[t * 4]     = pfx;
    base_l[t * 4 + 1] = pfx + s0;
    base_l[t * 4 + 2] = pfx + s0 + s1;
    base_l[t * 4 + 3] = pfx + s0 + s1 + s2;
    cur_l[t * 4]     = base_l[t * 4];
    cur_l[t * 4 + 1] = base_l[t * 4 + 1];
    cur_l[t * 4 + 2] = base_l[t * 4 + 2];
    cur_l[t * 4 + 3] = base_l[t * 4 + 3];
    __syncthreads();

    // one global cursor atomic per nonempty bin
    for (int i = t; i < NBINS; i += 256) {
        int c = hist[i];
        if (c) gbase[i] = atomicAdd(&gcur[i * CSTRIDE], c);
    }
    // scatter into LDS staging (sorted by bin)
    #pragma unroll
    for (int j = 0; j < EPT; ++j) {
        if (ok[j]) {
            int b = (int)((w[j] >> 22) & 0x3ff);
            int p = atomicAdd(&cur_l[b], 1);
            stage[p] = w[j];
        }
    }
    __syncthreads();

    // coalesced run write-out
    int cnt = min(n - c0, CHUNK);
    for (int p = t; p < cnt; p += 256) {
        u64 ww = stage[p];
        int b = (int)((ww >> 22) & 0x3ff);
        int g = gbase[b] + (p - base_l[b]);
        if (g < cap) eg[(size_t)b * cap + g] = ww;
    }
}

// ---------------------------------------------------------------------------
// Level 2: sort within each bin by key = row6*8 + colPhase3 -> exact per-row
// CSR segments (rows stay contiguous across their 8 phases), with each row's
// edges grouped into 8 col-phases (~1.6 MB of hpk each) so concurrent spmm_h
// waves sweep hpk in roughly aligned phases (better per-XCD L2 hit rate).
// For X bins, col < 256 -> phase 0 always (harmless).
// Grid = 2*NBINS: blocks [0,NBINS) = X, rest = adj.
// ---------------------------------------------------------------------------
__global__ __launch_bounds__(256) void rowsort(
        const int* __restrict__ gcur_x, const u64* __restrict__ egx,
        unsigned* __restrict__ e4x, int* __restrict__ rptr_x, int* __restrict__ rcnt_x,
        const int* __restrict__ gcur_a, const u64* __restrict__ ega,
        unsigned* __restrict__ e4a, int* __restrict__ rptr_a, int* __restrict__ rcnt_a) {
    __shared__ u64 stage[CAPBA];        // 20.8 KB
    __shared__ unsigned sorted[CAPBA];  // 10.4 KB
    __shared__ int hist[SBINS], ptrl[SBINS + 1], curl[SBINS];
    __shared__ int tsum[256];

    int t = threadIdx.x;
    int bin, cap;
    const u64* eg;
    unsigned* e4;
    int *rptr, *rcnt;
    int cnt;
    if (blockIdx.x < NBINS) {
        bin = blockIdx.x; cap = CAPBX; eg = egx; e4 = e4x;
        rptr = rptr_x; rcnt = rcnt_x;
        cnt = min(gcur_x[bin * CSTRIDE], cap);
    } else {
        bin = blockIdx.x - NBINS; cap = CAPBA; eg = ega; e4 = e4a;
        rptr = rptr_a; rcnt = rcnt_a;
        cnt = min(gcur_a[bin * CSTRIDE], cap);
    }
    size_t base = (size_t)bin * cap;

    for (int i = t; i < cnt; i += 256) stage[i] = eg[base + i];
    hist[t] = 0; hist[t + 256] = 0;
    __syncthreads();

    for (int i = t; i < cnt; i += 256) {
        u64 w = stage[i];
        int key = ((int)((w >> 16) & 63) << 3) | ((int)(w & 0xffffu) >> 13);
        atomicAdd(&hist[key], 1);
    }
    __syncthreads();

    // exclusive scan over 512 bins (2/thread + Hillis-Steele)
    int s0 = hist[t * 2], s1 = hist[t * 2 + 1];
    int tot = s0 + s1;
    tsum[t] = tot;
    __syncthreads();
    for (int off = 1; off < 256; off <<= 1) {
        int v = (t >= off) ? tsum[t - off] : 0;
        __syncthreads();
        tsum[t] += v;
        __syncthreads();
    }
    int pfx = tsum[t] - tot;
    ptrl[t * 2]     = pfx;
    ptrl[t * 2 + 1] = pfx + s0;
    curl[t * 2]     = pfx;
    curl[t * 2 + 1] = pfx + s0;
    if (t == 0) ptrl[SBINS] = cnt;
    __syncthreads();

    for (int i = t; i < cnt; i += 256) {
        u64 w = stage[i];
        int key = ((int)((w >> 16) & 63) << 3) | ((int)(w & 0xffffu) >> 13);
        int p = atomicAdd(&curl[key], 1);
        unsigned uv = (unsigned)(w >> 32);
        uv = (uv + 0x7fffu + ((uv >> 16) & 1u)) & 0xffff0000u;   // bf16 in hi16
        sorted[p] = (unsigned)(w & 0xffffu) | uv;
    }
    __syncthreads();

    for (int i = t; i < cnt; i += 256) e4[base + i] = sorted[i];
    if (t < 64) {
        int g = bin * RPB + t;
        if (g < N_NODES) {
            int b0 = ptrl[t * 8];
            rptr[g] = (int)base + b0;
            rcnt[g] = ptrl[(t + 1) * 8] - b0;   // row contiguous across phases
        }
    }
}

// ---------------------------------------------------------------------------
// SpMM 1: h(bf16) = X * W.  One wave per row; lane owns dims {2l,2l+1};
// W gathered as float2 from global (128 KB -> L2-resident); 8-way unroll.
// ---------------------------------------------------------------------------
__global__ void spmm_w(const int* __restrict__ rptr, const int* __restrict__ rcnt,
                       const unsigned* __restrict__ e4,
                       const float2* __restrict__ Wt, unsigned* __restrict__ hpk,
                       int nrows) {
    int wave = (blockIdx.x * blockDim.x + threadIdx.x) >> 6;
    int lane = threadIdx.x & 63;
    if (wave >= nrows) return;

    int s   = rptr[wave];
    int end = s + rcnt[wave];
    float2 acc = make_float2(0.0f, 0.0f);

    int e = s;
    for (; e + 7 < end; e += 8) {
        unsigned u0 = e4[e],     u1 = e4[e + 1], u2 = e4[e + 2], u3 = e4[e + 3];
        unsigned u4 = e4[e + 4], u5 = e4[e + 5], u6 = e4[e + 6], u7 = e4[e + 7];
        float2 a0 = Wt[(size_t)(u0 & 0xffffu) * OD2 + lane];
        float2 a1 = Wt[(size_t)(u1 & 0xffffu) * OD2 + lane];
        float2 a2 = Wt[(size_t)(u2 & 0xffffu) * OD2 + lane];
        float2 a3 = Wt[(size_t)(u3 & 0xffffu) * OD2 + lane];
        float2 a4 = Wt[(size_t)(u4 & 0xffffu) * OD2 + lane];
        float2 a5 = Wt[(size_t)(u5 & 0xffffu) * OD2 + lane];
        float2 a6 = Wt[(size_t)(u6 & 0xffffu) * OD2 + lane];
        float2 a7 = Wt[(size_t)(u7 & 0xffffu) * OD2 + lane];
        float v0 = __uint_as_float(u0 & 0xffff0000u), v1 = __uint_as_float(u1 & 0xffff0000u);
        float v2 = __uint_as_float(u2 & 0xffff0000u), v3 = __uint_as_float(u3 & 0xffff0000u);
        float v4 = __uint_as_float(u4 & 0xffff0000u), v5 = __uint_as_float(u5 & 0xffff0000u);
        float v6 = __uint_as_float(u6 & 0xffff0000u), v7 = __uint_as_float(u7 & 0xffff0000u);
        acc.x += v0 * a0.x + v1 * a1.x + v2 * a2.x + v3 * a3.x
               + v4 * a4.x + v5 * a5.x + v6 * a6.x + v7 * a7.x;
        acc.y += v0 * a0.y + v1 * a1.y + v2 * a2.y + v3 * a3.y
               + v4 * a4.y + v5 * a5.y + v6 * a6.y + v7 * a7.y;
    }
    for (; e < end; ++e) {
        unsigned u0 = e4[e];
        float2 a = Wt[(size_t)(u0 & 0xffffu) * OD2 + lane];
        float v0 = __uint_as_float(u0 & 0xffff0000u);
        acc.x += v0 * a.x;
        acc.y += v0 * a.y;
    }
    hpk[(size_t)wave * OD2 + lane] = pack_bf16x2(acc.x, acc.y);
}

// ---------------------------------------------------------------------------
// SpMM 2 + ReLU: out = relu(A * h).  One wave per row; gathers packed-bf16
// h rows (256 B/row), edges pre-grouped by col-phase; 8-way unroll.
// ---------------------------------------------------------------------------
__global__ void spmm_h(const int* __restrict__ rptr, const int* __restrict__ rcnt,
                       const unsigned* __restrict__ e4,
                       const unsigned* __restrict__ hpk, float2* __restrict__ outm,
                       int nrows) {
    int wave = (blockIdx.x * blockDim.x + threadIdx.x) >> 6;
    int lane = threadIdx.x & 63;
    if (wave >= nrows) return;

    int s   = rptr[wave];
    int end = s + rcnt[wave];
    float2 acc = make_float2(0.0f, 0.0f);

    int e = s;
    for (; e + 7 < end; e += 8) {
        unsigned u0 = e4[e],     u1 = e4[e + 1], u2 = e4[e + 2], u3 = e4[e + 3];
        unsigned u4 = e4[e + 4], u5 = e4[e + 5], u6 = e4[e + 6], u7 = e4[e + 7];
        unsigned h0 = hpk[(size_t)(u0 & 0xffffu) * OD2 + lane];
        unsigned h1 = hpk[(size_t)(u1 & 0xffffu) * OD2 + lane];
        unsigned h2 = hpk[(size_t)(u2 & 0xffffu) * OD2 + lane];
        unsigned h3 = hpk[(size_t)(u3 & 0xffffu) * OD2 + lane];
        unsigned h4 = hpk[(size_t)(u4 & 0xffffu) * OD2 + lane];
        unsigned h5 = hpk[(size_t)(u5 & 0xffffu) * OD2 + lane];
        unsigned h6 = hpk[(size_t)(u6 & 0xffffu) * OD2 + lane];
        unsigned h7 = hpk[(size_t)(u7 & 0xffffu) * OD2 + lane];
        float v0 = __uint_as_float(u0 & 0xffff0000u), v1 = __uint_as_float(u1 & 0xffff0000u);
        float v2 = __uint_as_float(u2 & 0xffff0000u), v3 = __uint_as_float(u3 & 0xffff0000u);
        float v4 = __uint_as_float(u4 & 0xffff0000u), v5 = __uint_as_float(u5 & 0xffff0000u);
        float v6 = __uint_as_float(u6 & 0xffff0000u), v7 = __uint_as_float(u7 & 0xffff0000u);
        float2 a0 = unpack_bf16x2(h0), a1 = unpack_bf16x2(h1);
        float2 a2 = unpack_bf16x2(h2), a3 = unpack_bf16x2(h3);
        float2 a4 = unpack_bf16x2(h4), a5 = unpack_bf16x2(h5);
        float2 a6 = unpack_bf16x2(h6), a7 = unpack_bf16x2(h7);
        acc.x += v0 * a0.x + v1 * a1.x + v2 * a2.x + v3 * a3.x
               + v4 * a4.x + v5 * a5.x + v6 * a6.x + v7 * a7.x;
        acc.y += v0 * a0.y + v1 * a1.y + v2 * a2.y + v3 * a3.y
               + v4 * a4.y + v5 * a5.y + v6 * a6.y + v7 * a7.y;
    }
    for (; e < end; ++e) {
        unsigned u0 = e4[e];
        float2 a = unpack_bf16x2(hpk[(size_t)(u0 & 0xffffu) * OD2 + lane]);
        float v0 = __uint_as_float(u0 & 0xffff0000u);
        acc.x += v0 * a.x;
        acc.y += v0 * a.y;
    }
    acc.x = fmaxf(acc.x, 0.0f);
    acc.y = fmaxf(acc.y, 0.0f);
    outm[(size_t)wave * OD2 + lane] = acc;
}

extern "C" void kernel_launch(void* const* d_in, const int* in_sizes, int n_in,
                              void* d_out, int out_size, void* d_ws, size_t ws_size,
                              hipStream_t stream) {
    const int*   x_rows     = (const int*)d_in[0];
    const int*   x_cols     = (const int*)d_in[1];
    const float* x_vals     = (const float*)d_in[2];
    const float* drop_noise = (const float*)d_in[3];
    const int*   adj_rows   = (const int*)d_in[4];
    const int*   adj_cols   = (const int*)d_in[5];
    const float* adj_vals   = (const float*)d_in[6];
    const float* W          = (const float*)d_in[7];

    const int nnz = in_sizes[0];   // 800000
    const int ne  = in_sizes[4];   // 1600000

    float* out = (float*)d_out;

    // ---- workspace layout (~52 MB) -----------------------------------------
    char* base = (char*)d_ws;
    unsigned* hpk = (unsigned*)base;                                    // 12.8 MB
    u64* egx = (u64*)(base + (size_t)N_NODES * OD2 * sizeof(unsigned)); // 8.8 MB
    u64* ega = egx + (size_t)NBINS * CAPBX;                             // 16.3 MB
    unsigned* e4x = (unsigned*)(ega + (size_t)NBINS * CAPBA);           // 4.4 MB
    unsigned* e4a = e4x + (size_t)NBINS * CAPBX;                        // 8.1 MB
    int* rptr_x = (int*)(e4a + (size_t)NBINS * CAPBA);                  // 200 KB
    int* rcnt_x = rptr_x + N_NODES;
    int* rptr_a = rcnt_x + N_NODES;
    int* rcnt_a = rptr_a + N_NODES;
    int* gcur_x = rcnt_a + N_NODES;                                     // 25 KB
    int* gcur_a = gcur_x + NBINS * CSTRIDE;

    hipMemsetAsync(gcur_x, 0, 2 * (size_t)NBINS * CSTRIDE * sizeof(int), stream);

    const int BXC = (nnz + CHUNK - 1) / CHUNK;   // 196
    const int BAC = (ne + CHUNK - 1) / CHUNK;    // 391
    const int BSPW = (N_NODES * 64 + 255) / 256; // 12500

    // L1: bin partition (coalesced run writes)
    partition<<<BXC + BAC, 256, 0, stream>>>(
        x_rows, x_cols, x_vals, drop_noise, nnz,
        adj_rows, adj_cols, adj_vals, ne,
        gcur_x, egx, gcur_a, ega, BXC);

    // L2: per-row CSR within bins, col-phase ordered, 4 B packed edges
    rowsort<<<2 * NBINS, 256, 0, stream>>>(
        gcur_x, egx, e4x, rptr_x, rcnt_x,
        gcur_a, ega, e4a, rptr_a, rcnt_a);

    // SpMM 1: h(bf16) = X * W
    spmm_w<<<BSPW, 256, 0, stream>>>(rptr_x, rcnt_x, e4x,
                                     (const float2*)W, hpk, N_NODES);

    // SpMM 2 + ReLU: out = relu(A * h)
    spmm_h<<<BSPW, 256, 0, stream>>>(rptr_a, rcnt_a, e4a, hpk,
                                     (float2*)out, N_NODES);
}

// Round 13
// 210.228 us; speedup vs baseline: 1.2067x; 1.0456x over previous
//
#include <hip/hip_runtime.h>

#define N_NODES 50000
#define IN_DIM  256
#define OUT_DIM 128
#define OD2     64       // packed bf16 pairs / float2 per 128-dim row
#define NBINS   782      // bin = row >> 6  (64 rows per bin)
#define RPB     64
#define CHUNK   4096     // edges per partition block (round-10/12 proven)
#define EPT     16       // edges per thread in partition (CHUNK/256)
#define CAPBX   1408     // X edges per bin: mean 1024, +12 sigma
#define CAPBA   2600     // adj edges per bin: mean 2048, +12 sigma
#define CSTRIDE 8        // bin counters padded to one 32B sector
#define SBINS   512      // adj rowsort bins: row6 * 8 + col-phase3

typedef unsigned long long u64;

// ---------------------------------------------------------------------------
// bf16 helpers (RNE).
// ---------------------------------------------------------------------------
__device__ __forceinline__ unsigned pack_bf16x2(float a, float b) {
    unsigned ua = __float_as_uint(a), ub = __float_as_uint(b);
    ua = (ua + 0x7fffu + ((ua >> 16) & 1u)) >> 16;
    ub = (ub + 0x7fffu + ((ub >> 16) & 1u)) >> 16;
    return ua | (ub << 16);
}
__device__ __forceinline__ float2 unpack_bf16x2(unsigned u) {
    return make_float2(__uint_as_float(u << 16),
                       __uint_as_float(u & 0xffff0000u));
}

// Edge word (u64): [63:32] = f32 val bits, [31:16] = row, [15:0] = col.
// Packed edge (u32): [31:16] = bf16 val bits, [15:0] = col.

// ---------------------------------------------------------------------------
// Level 1: partition into 782 row-bins.  LDS counting-sort each 4096-edge
// chunk by bin, one global cursor atomic per (block, nonempty bin), write
// runs contiguously (coalesced).  Blocks [0,bx) = X (keep_prob=1 dropout,
// faithful); rest = adj.  (Round-10/12 proven version, unchanged.)
// ---------------------------------------------------------------------------
__global__ __launch_bounds__(256) void partition(
        const int* __restrict__ xr, const int* __restrict__ xc,
        const float* __restrict__ xv, const float* __restrict__ dn, int nnz,
        const int* __restrict__ ar, const int* __restrict__ ac,
        const float* __restrict__ av, int ne,
        int* __restrict__ gcur_x, u64* __restrict__ egx,
        int* __restrict__ gcur_a, u64* __restrict__ ega, int bx) {
    __shared__ u64 stage[CHUNK];          // 32 KB
    __shared__ int hist[1024];            // zero-padded past NBINS
    __shared__ int base_l[1024];
    __shared__ int cur_l[1024];
    __shared__ int gbase[1024];
    __shared__ int tsum[256];

    int t = threadIdx.x;
    const int *rows, *cols;
    const float *vals, *noise = nullptr;
    int n, c0, cap;
    int* gcur;
    u64* eg;
    if (blockIdx.x < bx) {
        rows = xr; cols = xc; vals = xv; noise = dn; n = nnz;
        c0 = blockIdx.x * CHUNK; gcur = gcur_x; eg = egx; cap = CAPBX;
    } else {
        rows = ar; cols = ac; vals = av; n = ne;
        c0 = (blockIdx.x - bx) * CHUNK; gcur = gcur_a; eg = ega; cap = CAPBA;
    }

    for (int i = t; i < 1024; i += 256) hist[i] = 0;
    __syncthreads();

    u64 w[EPT];
    bool ok[EPT];
    #pragma unroll
    for (int j = 0; j < EPT; ++j) {
        int i = c0 + j * 256 + t;
        ok[j] = (i < n);
        if (ok[j]) {
            int r = rows[i], c = cols[i];
            float v = vals[i];
            if (noise) v *= floorf(1.0f + noise[i]);
            w[j] = ((u64)__float_as_uint(v) << 32) | ((unsigned)r << 16) | (unsigned)c;
            atomicAdd(&hist[r >> 6], 1);
        }
    }
    __syncthreads();

    // exclusive scan of hist (1024 entries, 4/thread + Hillis-Steele)
    int s0 = hist[t * 4], s1 = hist[t * 4 + 1], s2 = hist[t * 4 + 2], s3 = hist[t * 4 + 3];
    int tot = s0 + s1 + s2 + s3;
    tsum[t] = tot;
    __syncthreads();
    for (int off = 1; off < 256; off <<= 1) {
        int v = (t >= off) ? tsum[t - off] : 0;
        __syncthreads();
        tsum[t] += v;
        __syncthreads();
    }
    int pfx = tsum[t] - tot;
    base_l[t * 4]     = pfx;
    base_l[t * 4 + 1] = pfx + s0;
    base_l[t * 4 + 2] = pfx + s0 + s1;
    base_l[t * 4 + 3] = pfx + s0 + s1 + s2;
    cur_l[t * 4]     = base_l[t * 4];
    cur_l[t * 4 + 1] = base_l[t * 4 + 1];
    cur_l[t * 4 + 2] = base_l[t * 4 + 2];
    cur_l[t * 4 + 3] = base_l[t * 4 + 3];
    __syncthreads();

    // one global cursor atomic per nonempty bin
    for (int i = t; i < NBINS; i += 256) {
        int c = hist[i];
        if (c) gbase[i] = atomicAdd(&gcur[i * CSTRIDE], c);
    }
    // scatter into LDS staging (sorted by bin)
    #pragma unroll
    for (int j = 0; j < EPT; ++j) {
        if (ok[j]) {
            int b = (int)((w[j] >> 22) & 0x3ff);
            int p = atomicAdd(&cur_l[b], 1);
            stage[p] = w[j];
        }
    }
    __syncthreads();

    // coalesced run write-out
    int cnt = min(n - c0, CHUNK);
    for (int p = t; p < cnt; p += 256) {
        u64 ww = stage[p];
        int b = (int)((ww >> 22) & 0x3ff);
        int g = gbase[b] + (p - base_l[b]);
        if (g < cap) eg[(size_t)b * cap + g] = ww;
    }
}

// ---------------------------------------------------------------------------
// K2 fused (grid-split):
//   blocks [0, NBINS):    X bins — rowsort in LDS, then SpMM h = X*W directly
//                         from LDS-sorted edges (no e4x global round-trip).
//                         Edge reads are LDS broadcasts; W gathers L2-hot;
//                         hpk written once, coalesced (256 B per row).
//   blocks [NBINS, 2N):   adj bins — rowsort with 512-way key
//                         (row6*8 + colPhase3), scattered writes go directly
//                         to the bin's 10 KB L2-resident global window.
// ---------------------------------------------------------------------------
__global__ __launch_bounds__(256) void k2_fused(
        const int* __restrict__ gcur_x, const u64* __restrict__ egx,
        const float2* __restrict__ Wt, unsigned* __restrict__ hpk,
        const int* __restrict__ gcur_a, const u64* __restrict__ ega,
        unsigned* __restrict__ e4a, int* __restrict__ rptr_a, int* __restrict__ rcnt_a) {
    __shared__ u64 stage[CAPBA];        // 20.8 KB (X path uses first CAPBX)
    __shared__ unsigned sortedx[CAPBX]; // 5.6 KB (X path only)
    __shared__ int hist[SBINS], ptrl[SBINS + 1], curl[SBINS];
    __shared__ int tsum[256];

    int t = threadIdx.x;

    if (blockIdx.x < NBINS) {
        // ================= X path: rowsort(64 keys) + fused SpMM ============
        int bin = blockIdx.x;
        int cnt = min(gcur_x[bin * CSTRIDE], CAPBX);
        size_t base = (size_t)bin * CAPBX;

        for (int i = t; i < cnt; i += 256) stage[i] = egx[base + i];
        if (t < 64) hist[t] = 0;
        __syncthreads();

        for (int i = t; i < cnt; i += 256)
            atomicAdd(&hist[(int)((stage[i] >> 16) & 63)], 1);
        __syncthreads();

        // wave-0 shfl scan over the 64 row counts
        if (t < 64) {
            int v = hist[t];
            int incl = v;
            #pragma unroll
            for (int off = 1; off < 64; off <<= 1) {
                int o = __shfl_up(incl, off, 64);
                if (t >= off) incl += o;
            }
            ptrl[t] = incl - v;
            curl[t] = incl - v;
        }
        __syncthreads();

        for (int i = t; i < cnt; i += 256) {
            u64 w = stage[i];
            int r = (int)((w >> 16) & 63);
            int p = atomicAdd(&curl[r], 1);
            unsigned uv = (unsigned)(w >> 32);
            uv = (uv + 0x7fffu + ((uv >> 16) & 1u)) & 0xffff0000u;
            sortedx[p] = (unsigned)(w & 0xffffu) | uv;
        }
        __syncthreads();

        // fused SpMM: wave wv handles rows wv, wv+4, ... (16 rows each)
        int lane = t & 63, wv = t >> 6;
        for (int r = wv; r < RPB; r += 4) {
            int g = bin * RPB + r;
            if (g >= N_NODES) break;
            int s = ptrl[r];
            int end = s + hist[r];
            float2 acc = make_float2(0.0f, 0.0f);
            int e = s;
            for (; e + 3 < end; e += 4) {
                unsigned u0 = sortedx[e],     u1 = sortedx[e + 1];
                unsigned u2 = sortedx[e + 2], u3 = sortedx[e + 3];
                float2 a0 = Wt[(size_t)(u0 & 0xffffu) * OD2 + lane];
                float2 a1 = Wt[(size_t)(u1 & 0xffffu) * OD2 + lane];
                float2 a2 = Wt[(size_t)(u2 & 0xffffu) * OD2 + lane];
                float2 a3 = Wt[(size_t)(u3 & 0xffffu) * OD2 + lane];
                float v0 = __uint_as_float(u0 & 0xffff0000u);
                float v1 = __uint_as_float(u1 & 0xffff0000u);
                float v2 = __uint_as_float(u2 & 0xffff0000u);
                float v3 = __uint_as_float(u3 & 0xffff0000u);
                acc.x += v0 * a0.x + v1 * a1.x + v2 * a2.x + v3 * a3.x;
                acc.y += v0 * a0.y + v1 * a1.y + v2 * a2.y + v3 * a3.y;
            }
            for (; e < end; ++e) {
                unsigned u0 = sortedx[e];
                float2 a = Wt[(size_t)(u0 & 0xffffu) * OD2 + lane];
                float v0 = __uint_as_float(u0 & 0xffff0000u);
                acc.x += v0 * a.x;
                acc.y += v0 * a.y;
            }
            hpk[(size_t)g * OD2 + lane] = pack_bf16x2(acc.x, acc.y);
        }
        return;
    }

    // ================= adj path: rowsort with col-phase keys ================
    int bin = blockIdx.x - NBINS;
    int cnt = min(gcur_a[bin * CSTRIDE], CAPBA);
    size_t base = (size_t)bin * CAPBA;

    for (int i = t; i < cnt; i += 256) stage[i] = ega[base + i];
    hist[t] = 0; hist[t + 256] = 0;
    __syncthreads();

    for (int i = t; i < cnt; i += 256) {
        u64 w = stage[i];
        int key = ((int)((w >> 16) & 63) << 3) | ((int)(w & 0xffffu) >> 13);
        atomicAdd(&hist[key], 1);
    }
    __syncthreads();

    // exclusive scan over 512 bins (2/thread + Hillis-Steele)
    int s0 = hist[t * 2], s1 = hist[t * 2 + 1];
    int tot = s0 + s1;
    tsum[t] = tot;
    __syncthreads();
    for (int off = 1; off < 256; off <<= 1) {
        int v = (t >= off) ? tsum[t - off] : 0;
        __syncthreads();
        tsum[t] += v;
        __syncthreads();
    }
    int pfx = tsum[t] - tot;
    ptrl[t * 2]     = pfx;
    ptrl[t * 2 + 1] = pfx + s0;
    curl[t * 2]     = pfx;
    curl[t * 2 + 1] = pfx + s0;
    if (t == 0) ptrl[SBINS] = cnt;
    __syncthreads();

    // scatter DIRECTLY to the bin's global window (10 KB, L2-resident;
    // lines fully written before eviction -> coalesced writeback)
    for (int i = t; i < cnt; i += 256) {
        u64 w = stage[i];
        int key = ((int)((w >> 16) & 63) << 3) | ((int)(w & 0xffffu) >> 13);
        int p = atomicAdd(&curl[key], 1);
        unsigned uv = (unsigned)(w >> 32);
        uv = (uv + 0x7fffu + ((uv >> 16) & 1u)) & 0xffff0000u;
        e4a[base + p] = (unsigned)(w & 0xffffu) | uv;
    }

    if (t < 64) {
        int g = bin * RPB + t;
        if (g < N_NODES) {
            int b0 = ptrl[t * 8];
            rptr_a[g] = (int)base + b0;
            rcnt_a[g] = ptrl[(t + 1) * 8] - b0;   // row contiguous across phases
        }
    }
}

// ---------------------------------------------------------------------------
// SpMM 2 + ReLU: out = relu(A * h).  One wave per row; gathers packed-bf16
// h rows (256 B/row), edges pre-grouped by col-phase; 8-way unroll.
// ---------------------------------------------------------------------------
__global__ void spmm_h(const int* __restrict__ rptr, const int* __restrict__ rcnt,
                       const unsigned* __restrict__ e4,
                       const unsigned* __restrict__ hpk, float2* __restrict__ outm,
                       int nrows) {
    int wave = (blockIdx.x * blockDim.x + threadIdx.x) >> 6;
    int lane = threadIdx.x & 63;
    if (wave >= nrows) return;

    int s   = rptr[wave];
    int end = s + rcnt[wave];
    float2 acc = make_float2(0.0f, 0.0f);

    int e = s;
    for (; e + 7 < end; e += 8) {
        unsigned u0 = e4[e],     u1 = e4[e + 1], u2 = e4[e + 2], u3 = e4[e + 3];
        unsigned u4 = e4[e + 4], u5 = e4[e + 5], u6 = e4[e + 6], u7 = e4[e + 7];
        unsigned h0 = hpk[(size_t)(u0 & 0xffffu) * OD2 + lane];
        unsigned h1 = hpk[(size_t)(u1 & 0xffffu) * OD2 + lane];
        unsigned h2 = hpk[(size_t)(u2 & 0xffffu) * OD2 + lane];
        unsigned h3 = hpk[(size_t)(u3 & 0xffffu) * OD2 + lane];
        unsigned h4 = hpk[(size_t)(u4 & 0xffffu) * OD2 + lane];
        unsigned h5 = hpk[(size_t)(u5 & 0xffffu) * OD2 + lane];
        unsigned h6 = hpk[(size_t)(u6 & 0xffffu) * OD2 + lane];
        unsigned h7 = hpk[(size_t)(u7 & 0xffffu) * OD2 + lane];
        float v0 = __uint_as_float(u0 & 0xffff0000u), v1 = __uint_as_float(u1 & 0xffff0000u);
        float v2 = __uint_as_float(u2 & 0xffff0000u), v3 = __uint_as_float(u3 & 0xffff0000u);
        float v4 = __uint_as_float(u4 & 0xffff0000u), v5 = __uint_as_float(u5 & 0xffff0000u);
        float v6 = __uint_as_float(u6 & 0xffff0000u), v7 = __uint_as_float(u7 & 0xffff0000u);
        float2 a0 = unpack_bf16x2(h0), a1 = unpack_bf16x2(h1);
        float2 a2 = unpack_bf16x2(h2), a3 = unpack_bf16x2(h3);
        float2 a4 = unpack_bf16x2(h4), a5 = unpack_bf16x2(h5);
        float2 a6 = unpack_bf16x2(h6), a7 = unpack_bf16x2(h7);
        acc.x += v0 * a0.x + v1 * a1.x + v2 * a2.x + v3 * a3.x
               + v4 * a4.x + v5 * a5.x + v6 * a6.x + v7 * a7.x;
        acc.y += v0 * a0.y + v1 * a1.y + v2 * a2.y + v3 * a3.y
               + v4 * a4.y + v5 * a5.y + v6 * a6.y + v7 * a7.y;
    }
    for (; e < end; ++e) {
        unsigned u0 = e4[e];
        float2 a = unpack_bf16x2(hpk[(size_t)(u0 & 0xffffu) * OD2 + lane]);
        float v0 = __uint_as_float(u0 & 0xffff0000u);
        acc.x += v0 * a.x;
        acc.y += v0 * a.y;
    }
    acc.x = fmaxf(acc.x, 0.0f);
    acc.y = fmaxf(acc.y, 0.0f);
    outm[(size_t)wave * OD2 + lane] = acc;
}

extern "C" void kernel_launch(void* const* d_in, const int* in_sizes, int n_in,
                              void* d_out, int out_size, void* d_ws, size_t ws_size,
                              hipStream_t stream) {
    const int*   x_rows     = (const int*)d_in[0];
    const int*   x_cols     = (const int*)d_in[1];
    const float* x_vals     = (const float*)d_in[2];
    const float* drop_noise = (const float*)d_in[3];
    const int*   adj_rows   = (const int*)d_in[4];
    const int*   adj_cols   = (const int*)d_in[5];
    const float* adj_vals   = (const float*)d_in[6];
    const float* W          = (const float*)d_in[7];

    const int nnz = in_sizes[0];   // 800000
    const int ne  = in_sizes[4];   // 1600000

    float* out = (float*)d_out;

    // ---- workspace layout (~46 MB) -----------------------------------------
    char* base = (char*)d_ws;
    unsigned* hpk = (unsigned*)base;                                    // 12.8 MB
    u64* egx = (u64*)(base + (size_t)N_NODES * OD2 * sizeof(unsigned)); // 8.8 MB
    u64* ega = egx + (size_t)NBINS * CAPBX;                             // 16.3 MB
    unsigned* e4a = (unsigned*)(ega + (size_t)NBINS * CAPBA);           // 8.1 MB
    int* rptr_a = (int*)(e4a + (size_t)NBINS * CAPBA);                  // 200 KB
    int* rcnt_a = rptr_a + N_NODES;
    int* gcur_x = rcnt_a + N_NODES;                                     // 25 KB
    int* gcur_a = gcur_x + NBINS * CSTRIDE;

    hipMemsetAsync(gcur_x, 0, 2 * (size_t)NBINS * CSTRIDE * sizeof(int), stream);

    const int BXC = (nnz + CHUNK - 1) / CHUNK;   // 196
    const int BAC = (ne + CHUNK - 1) / CHUNK;    // 391
    const int BSPH = (N_NODES * 64 + 255) / 256; // 12500

    // L1: bin partition (coalesced run writes)
    partition<<<BXC + BAC, 256, 0, stream>>>(
        x_rows, x_cols, x_vals, drop_noise, nnz,
        adj_rows, adj_cols, adj_vals, ne,
        gcur_x, egx, gcur_a, ega, BXC);

    // K2: X rowsort+SpMM fused (LDS edges)  ||  adj rowsort (independent)
    k2_fused<<<2 * NBINS, 256, 0, stream>>>(
        gcur_x, egx, (const float2*)W, hpk,
        gcur_a, ega, e4a, rptr_a, rcnt_a);

    // K3: out = relu(A * h)
    spmm_h<<<BSPH, 256, 0, stream>>>(rptr_a, rcnt_a, e4a, hpk,
                                     (float2*)out, N_NODES);
}